// Round 5
// baseline (2077.408 us; speedup 1.0000x reference)
//
#include <hip/hip_runtime.h>
#include <hip/hip_cooperative_groups.h>

namespace cg = cooperative_groups;

#define NTOK   32768
#define DDIM   512
#define KCODES 8192
#define DK     (DDIM * KCODES)      // 4194304
#define DECAYF 0.8f
#define EPSF   1e-5f

using short8 = __attribute__((ext_vector_type(8))) short;
using f32x4  = __attribute__((ext_vector_type(4))) float;

// ---------------- ws layout (float offsets) ----------------
#define WS_ESUMT  0
#define WS_ONEHOT DK
#define WS_ENORM  (DK + 8192)
#define WS_SCAL   (DK + 16384)
#define WS_PART   (WS_SCAL + 64)
#define WS_EHI    (WS_PART + 2 * NTOK)
#define WS_ELO    (WS_EHI + DK / 2)

#define P_NBLK (8192 + 256 + 2048 + 32)   // 10528 virtual prep blocks
#define G_NBLK (64 * 256)                 // 16384 GEMM tiles
#define Q_NBLK (NTOK / 2)                 // 16384 gather blocks (2 tok each)
#define F_NBLK (256 * 16)                 // 4096 finalize tiles

__device__ __forceinline__ unsigned short bf16rne(float f) {
  unsigned u = __float_as_uint(f);
  unsigned r = u + 0x7FFFu + ((u >> 16) & 1u);
  return (unsigned short)(r >> 16);
}

__device__ __forceinline__ void gload_lds16(const unsigned short* g, unsigned short* l) {
  __builtin_amdgcn_global_load_lds(
      (const __attribute__((address_space(1))) unsigned int*)g,
      (__attribute__((address_space(3))) unsigned int*)l, 16, 0, 0);
}

// ================= single fused cooperative kernel =================
// Stage P: x bf16 split | embed transpose/split + e_norm | zero esumT | misc init
// Stage G: 3-product bf16-split MFMA dist GEMM + fused argmin (proven 128x128)
// Stage Q: gather quantize + scatter stats + loss
// Stage F: EMA finalize (avg/embed/ncs/loss)
__global__ __launch_bounds__(256, 3) void vq_fused_kernel(
    const float* __restrict__ x, const float* __restrict__ embed,
    const float* __restrict__ cluster_size, const float* __restrict__ embed_avg,
    float* __restrict__ out_quant, float* __restrict__ out_indf,
    float* __restrict__ out_loss, float* __restrict__ out_embed,
    float* __restrict__ out_ncs, float* __restrict__ out_avg,
    unsigned short* __restrict__ xhi, unsigned short* __restrict__ xlo,
    unsigned short* __restrict__ ehi, unsigned short* __restrict__ elo,
    float* __restrict__ e_norm, float* __restrict__ esumT,
    float* __restrict__ onehot, float* __restrict__ scal,
    unsigned long long* __restrict__ partials) {
  __shared__ __align__(16) unsigned short sbuf[4 * 128 * 32];   // 32 KB, stage-aliased
  cg::grid_group grid = cg::this_grid();
  const int tid = threadIdx.x;
  const int nb  = gridDim.x;

  // =================== Stage P: prep ===================
  {
    float* tile33 = (float*)sbuf;           // [32][33]
    float* part8  = tile33 + 32 * 33;       // [8][32]
    float* wred   = part8 + 8 * 32;         // [4]
    for (int bid = blockIdx.x; bid < P_NBLK; bid += nb) {
      if (bid < 8192) {
        // ---- split x into bf16 hi/lo ----
        const size_t i = ((size_t)bid * 256 + tid) * 8;
        const float4 v0 = *(const float4*)&x[i];
        const float4 v1 = *(const float4*)&x[i + 4];
        const float v[8] = {v0.x, v0.y, v0.z, v0.w, v1.x, v1.y, v1.z, v1.w};
        unsigned short h[8], l[8];
#pragma unroll
        for (int j = 0; j < 8; ++j) {
          h[j] = bf16rne(v[j]);
          l[j] = bf16rne(v[j] - __uint_as_float((unsigned)h[j] << 16));
        }
        uint4 H, L;
        H.x = h[0] | ((unsigned)h[1] << 16); H.y = h[2] | ((unsigned)h[3] << 16);
        H.z = h[4] | ((unsigned)h[5] << 16); H.w = h[6] | ((unsigned)h[7] << 16);
        L.x = l[0] | ((unsigned)l[1] << 16); L.y = l[2] | ((unsigned)l[3] << 16);
        L.z = l[4] | ((unsigned)l[5] << 16); L.w = l[6] | ((unsigned)l[7] << 16);
        *(uint4*)&xhi[i] = H;
        *(uint4*)&xlo[i] = L;
      } else if (bid < 8192 + 256) {
        // ---- transpose embed: 32 codes/block, full D, complete norm ----
        const int k0 = (bid - 8192) * 32;
        const int tx = tid & 31;
        const int ty = tid >> 5;
        float sq = 0.f;
#pragma unroll 1
        for (int d0 = 0; d0 < DDIM; d0 += 32) {
          __syncthreads();
#pragma unroll
          for (int j = 0; j < 4; ++j) {
            const int dl = ty + j * 8;
            const float v = embed[(size_t)(d0 + dl) * KCODES + k0 + tx];
            tile33[dl * 33 + tx] = v;
            sq += v * v;
          }
          __syncthreads();
#pragma unroll
          for (int j = 0; j < 4; ++j) {
            const int kl = ty + j * 8;
            const size_t idx = (size_t)(k0 + kl) * DDIM + d0 + tx;
            const float v = tile33[tx * 33 + kl];
            const unsigned short h = bf16rne(v);
            ehi[idx] = h;
            elo[idx] = bf16rne(v - __uint_as_float((unsigned)h << 16));
          }
        }
        part8[ty * 32 + tx] = sq;
        __syncthreads();
        if (ty == 0) {
          float s = 0.f;
#pragma unroll
          for (int j = 0; j < 8; ++j) s += part8[j * 32 + tx];
          e_norm[k0 + tx] = s;
        }
      } else if (bid < 8192 + 256 + 2048) {
        // ---- zero esumT ----
        const int zb = bid - (8192 + 256);
        const size_t off = (size_t)zb * 2048 + (size_t)tid * 8;
        const float4 z = {0.f, 0.f, 0.f, 0.f};
        *(float4*)&esumT[off] = z;
        *(float4*)&esumT[off + 4] = z;
      } else {
        // ---- misc init ----
        const int b = bid - (8192 + 256 + 2048);   // 0..31
        onehot[b * 256 + tid] = 0.f;
        const size_t pbase = (size_t)b * 1024 + (size_t)tid * 4;
        const ulonglong2 ff = {~0ull, ~0ull};
        *(ulonglong2*)&partials[pbase] = ff;
        *(ulonglong2*)&partials[pbase + 2] = ff;
        float s = cluster_size[b * 256 + tid];
#pragma unroll
        for (int off = 32; off > 0; off >>= 1) s += __shfl_down(s, off);
        if ((tid & 63) == 0) wred[tid >> 6] = s;
        __syncthreads();
        if (tid == 0) {
          scal[2 + b] = wred[0] + wred[1] + wred[2] + wred[3];
          if (b == 0) { scal[0] = 0.f; scal[1] = 0.f; }
        }
      }
      __syncthreads();
    }
  }
  __threadfence();
  grid.sync();

  // =================== Stage G: MFMA dist GEMM + argmin ===================
  {
    unsigned short* Ahs = sbuf;
    unsigned short* Als = sbuf + 4096;
    unsigned short* Bhs = sbuf + 8192;
    unsigned short* Bls = sbuf + 12288;

    const int wid = tid >> 6;
    const int lid = tid & 63;
    const int wrow = wid >> 1, wcol = wid & 1;
    const int m16 = lid & 15, kq = lid >> 4;
    const int srow = lid >> 2;
    const int gcol = ((lid & 3) ^ ((srow >> 1) & 3)) * 8;
    const int fsw = (kq ^ ((m16 >> 1) & 3)) * 8;

    for (int vb = blockIdx.x; vb < G_NBLK; vb += nb) {
      const int kbase   = (vb & 63) * 128;
      const int tokbase = (vb >> 6) * 128;

      f32x4 acc[4][4];
#pragma unroll
      for (int i = 0; i < 4; ++i)
#pragma unroll
        for (int j = 0; j < 4; ++j) acc[i][j] = (f32x4)0.f;

      const unsigned short* Ahg = xhi + (size_t)tokbase * DDIM;
      const unsigned short* Alg = xlo + (size_t)tokbase * DDIM;
      const unsigned short* Bhg = ehi + (size_t)kbase * DDIM;
      const unsigned short* Blg = elo + (size_t)kbase * DDIM;

#pragma unroll 1
      for (int d0 = 0; d0 < DDIM; d0 += 32) {
        __syncthreads();
#pragma unroll
        for (int p = 0; p < 2; ++p) {
          const int chunk = wid + p * 4;
          const size_t go = (size_t)(chunk * 16 + srow) * DDIM + d0 + gcol;
          gload_lds16(Ahg + go, &Ahs[chunk * 512]);
          gload_lds16(Alg + go, &Als[chunk * 512]);
          gload_lds16(Bhg + go, &Bhs[chunk * 512]);
          gload_lds16(Blg + go, &Bls[chunk * 512]);
        }
        __syncthreads();
        short8 bh[4], bl[4];
#pragma unroll
        for (int j = 0; j < 4; ++j) {
          const int r = (wcol * 64 + j * 16 + m16) * 32 + fsw;
          bh[j] = *(const short8*)&Bhs[r];
          bl[j] = *(const short8*)&Bls[r];
        }
#pragma unroll
        for (int i = 0; i < 4; ++i) {
          const int r = (wrow * 64 + i * 16 + m16) * 32 + fsw;
          const short8 ah = *(const short8*)&Ahs[r];
          const short8 al = *(const short8*)&Als[r];
#pragma unroll
          for (int j = 0; j < 4; ++j) {
            acc[i][j] = __builtin_amdgcn_mfma_f32_16x16x32_bf16(ah, bh[j], acc[i][j], 0, 0, 0);
            acc[i][j] = __builtin_amdgcn_mfma_f32_16x16x32_bf16(ah, bl[j], acc[i][j], 0, 0, 0);
            acc[i][j] = __builtin_amdgcn_mfma_f32_16x16x32_bf16(al, bh[j], acc[i][j], 0, 0, 0);
          }
        }
      }

      // ---- fused argmin epilogue: score = ||e_k||^2 - 2*dot ----
      float en[4];
#pragma unroll
      for (int j = 0; j < 4; ++j)
        en[j] = e_norm[kbase + wcol * 64 + j * 16 + m16];

      __syncthreads();
      unsigned long long* red = (unsigned long long*)Ahs;
#pragma unroll
      for (int i = 0; i < 4; ++i) {
#pragma unroll
        for (int r = 0; r < 4; ++r) {
          unsigned long long best = 0xFFFFFFFFFFFFFFFFull;
#pragma unroll
          for (int j = 0; j < 4; ++j) {
            const float s = en[j] - 2.0f * acc[i][j][r];
            unsigned u = __float_as_uint(s);
            u = (u & 0x80000000u) ? ~u : (u | 0x80000000u);
            const unsigned k = (unsigned)(kbase + wcol * 64 + j * 16 + m16);
            const unsigned long long c = ((unsigned long long)u << 32) | k;
            best = (c < best) ? c : best;
          }
#pragma unroll
          for (int s = 1; s < 16; s <<= 1) {
            const unsigned long long c = __shfl_xor(best, s);
            best = (c < best) ? c : best;
          }
          if (m16 == 0)
            red[(wrow * 64 + i * 16 + kq * 4 + r) * 2 + wcol] = best;
        }
      }
      __syncthreads();
      if (tid < 128) {
        const unsigned long long a0 = red[tid * 2], a1 = red[tid * 2 + 1];
        const unsigned long long m = (a0 < a1) ? a0 : a1;
        atomicMin(&partials[tokbase + tid], m);
      }
      __syncthreads();
    }
  }
  __threadfence();
  grid.sync();

  // =================== Stage Q: gather quantize + stats + loss ===================
  {
    int*   s_ind = (int*)sbuf;              // [2]
    float* wsum  = ((float*)sbuf) + 2;      // [4]
    const int sub = tid >> 7;
    const int t7  = tid & 127;
    for (int vb = blockIdx.x; vb < Q_NBLK; vb += nb) {
      const int n = vb * 2 + sub;
      if (t7 == 0) {
        const int k = (int)(partials[n] & 0xFFFFFFFFull);
        s_ind[sub] = k;
        out_indf[n] = (float)k;
        atomicAdd(&onehot[k], 1.0f);
      }
      __syncthreads();
      const int k = s_ind[sub];
      const int d4 = t7 * 4;
      const ushort4 h4 = *(const ushort4*)&ehi[(size_t)k * DDIM + d4];
      const ushort4 l4 = *(const ushort4*)&elo[(size_t)k * DDIM + d4];
      float4 e;
      e.x = __uint_as_float((unsigned)h4.x << 16) + __uint_as_float((unsigned)l4.x << 16);
      e.y = __uint_as_float((unsigned)h4.y << 16) + __uint_as_float((unsigned)l4.y << 16);
      e.z = __uint_as_float((unsigned)h4.z << 16) + __uint_as_float((unsigned)l4.z << 16);
      e.w = __uint_as_float((unsigned)h4.w << 16) + __uint_as_float((unsigned)l4.w << 16);
      const float4 xv = *(const float4*)&x[(size_t)n * DDIM + d4];
      *(float4*)&out_quant[(size_t)n * DDIM + d4] = e;
      atomicAdd(&esumT[(size_t)k * DDIM + d4 + 0], xv.x);
      atomicAdd(&esumT[(size_t)k * DDIM + d4 + 1], xv.y);
      atomicAdd(&esumT[(size_t)k * DDIM + d4 + 2], xv.z);
      atomicAdd(&esumT[(size_t)k * DDIM + d4 + 3], xv.w);
      const float dx0 = e.x - xv.x, dx1 = e.y - xv.y, dx2 = e.z - xv.z, dx3 = e.w - xv.w;
      float ls = dx0 * dx0 + dx1 * dx1 + dx2 * dx2 + dx3 * dx3;
#pragma unroll
      for (int off = 32; off > 0; off >>= 1) ls += __shfl_down(ls, off);
      if ((tid & 63) == 0) wsum[tid >> 6] = ls;
      __syncthreads();
      if (tid == 0)
        atomicAdd(&scal[0], wsum[0] + wsum[1] + wsum[2] + wsum[3]);
      __syncthreads();
    }
  }
  __threadfence();
  grid.sync();

  // =================== Stage F: finalize ===================
  {
    float* tile33 = (float*)sbuf;           // [32][33]
    float csum = 0.f;
#pragma unroll
    for (int b = 0; b < 32; ++b) csum += scal[2 + b];
    const float nsum = DECAYF * csum + (1.0f - DECAYF) * (float)NTOK;
    const int tx = tid & 31;
    const int ty = tid >> 5;
    for (int vb = blockIdx.x; vb < F_NBLK; vb += nb) {
      const int k0 = (vb & 255) * 32;
      const int d0 = (vb >> 8) * 32;
#pragma unroll
      for (int j = 0; j < 4; ++j) {
        const int kl = ty + j * 8;
        tile33[kl * 33 + tx] = esumT[(size_t)(k0 + kl) * DDIM + d0 + tx];
      }
      __syncthreads();
      const float ncs = DECAYF * cluster_size[k0 + tx] + (1.0f - DECAYF) * onehot[k0 + tx];
      const float csv = (ncs + EPSF) / (nsum + (float)KCODES * EPSF) * nsum;
#pragma unroll
      for (int j = 0; j < 4; ++j) {
        const int dl = ty + j * 8;
        const size_t idx = (size_t)(d0 + dl) * KCODES + k0 + tx;
        const float nea = DECAYF * embed_avg[idx] + (1.0f - DECAYF) * tile33[tx * 33 + dl];
        out_avg[idx] = nea;
        out_embed[idx] = nea / csv;
      }
      if ((vb >> 8) == 0 && ty == 0)
        out_ncs[k0 + tx] = ncs;
      if (vb == 0 && tid == 0)
        out_loss[0] = scal[0] * (1.0f / ((float)NTOK * (float)DDIM));
      __syncthreads();
    }
  }
}

extern "C" void kernel_launch(void* const* d_in, const int* in_sizes, int n_in,
                              void* d_out, int out_size, void* d_ws, size_t ws_size,
                              hipStream_t stream) {
  (void)in_sizes; (void)n_in; (void)out_size; (void)ws_size;
  const float* x            = (const float*)d_in[0];   // [NTOK, 512]
  const float* embed        = (const float*)d_in[1];   // [D, K]
  const float* cluster_size = (const float*)d_in[2];   // [K]
  const float* embed_avg    = (const float*)d_in[3];   // [D, K]

  float* out = (float*)d_out;
  float* out_quant = out;                               // 16777216
  float* out_indf  = out + 16777216;                    // 32768
  float* out_loss  = out + 16777216 + 32768;            // 1
  float* out_embed = out + 16777216 + 32768 + 1;        // 4194304 (odd offset)
  float* out_ncs   = out_embed + DK;                    // 8192
  float* out_avg   = out_ncs + KCODES;                  // 4194304

  float* ws = (float*)d_ws;
  float* esumT  = ws + WS_ESUMT;
  float* onehot = ws + WS_ONEHOT;
  float* e_norm = ws + WS_ENORM;
  float* scal   = ws + WS_SCAL;
  unsigned long long* partials = (unsigned long long*)(ws + WS_PART);
  unsigned short* ehi = (unsigned short*)(ws + WS_EHI);
  unsigned short* elo = (unsigned short*)(ws + WS_ELO);

  // x hi/lo scratch lives in the out_quant region; overwritten by stage Q later.
  unsigned short* xhi = (unsigned short*)d_out;
  unsigned short* xlo = xhi + (size_t)NTOK * DDIM;

  // grid = guaranteed co-resident blocks (occupancy query x 256 CUs, LDS-capped)
  static int perCU = -1;
  if (perCU < 0) {
    if (hipOccupancyMaxActiveBlocksPerMultiprocessor(&perCU, vq_fused_kernel, 256, 0)
            != hipSuccess || perCU < 1)
      perCU = 2;
  }
  int grid = perCU * 256;
  if (grid > 1280) grid = 1280;

  void* args[] = {
      (void*)&x, (void*)&embed, (void*)&cluster_size, (void*)&embed_avg,
      (void*)&out_quant, (void*)&out_indf, (void*)&out_loss, (void*)&out_embed,
      (void*)&out_ncs, (void*)&out_avg,
      (void*)&xhi, (void*)&xlo, (void*)&ehi, (void*)&elo,
      (void*)&e_norm, (void*)&esumT, (void*)&onehot, (void*)&scal,
      (void*)&partials};

  hipLaunchCooperativeKernel((const void*)vq_fused_kernel, dim3(grid), dim3(256),
                             args, 0, stream);
}

// Round 6
// 1505.543 us; speedup vs baseline: 1.3798x; 1.3798x over previous
//
#include <hip/hip_runtime.h>

#define NTOK   32768
#define DDIM   512
#define KCODES 8192
#define DK     (DDIM * KCODES)      // 4194304
#define DECAYF 0.8f
#define EPSF   1e-5f

using short8 = __attribute__((ext_vector_type(8))) short;
using f32x4  = __attribute__((ext_vector_type(4))) float;

// ---------------- ws layout (float offsets) ----------------
#define WS_ESUMT  0
#define WS_ONEHOT DK
#define WS_ENORM  (DK + 8192)
#define WS_SCAL   (DK + 16384)
#define WS_PART   (WS_SCAL + 64)
#define WS_EHI    (WS_PART + 2 * NTOK)
#define WS_ELO    (WS_EHI + DK / 2)

__device__ __forceinline__ unsigned short bf16rne(float f) {
  unsigned u = __float_as_uint(f);
  unsigned r = u + 0x7FFFu + ((u >> 16) & 1u);
  return (unsigned short)(r >> 16);
}

__device__ __forceinline__ void gload_lds16(const unsigned short* g, unsigned short* l) {
  __builtin_amdgcn_global_load_lds(
      (const __attribute__((address_space(1))) unsigned int*)g,
      (__attribute__((address_space(3))) unsigned int*)l, 16, 0, 0);
}

#define BAR() do { __builtin_amdgcn_sched_barrier(0); \
  __builtin_amdgcn_s_barrier(); __builtin_amdgcn_sched_barrier(0); } while (0)
#define VMCNT6() asm volatile("s_waitcnt vmcnt(6)" ::: "memory")
#define VMCNT8() asm volatile("s_waitcnt vmcnt(8)" ::: "memory")

// ============ K1: fused prep (unchanged from R4) ============
__global__ __launch_bounds__(256) void prep_kernel(
    const float* __restrict__ x, const float* __restrict__ embed,
    const float* __restrict__ cluster_size,
    unsigned short* __restrict__ xhi, unsigned short* __restrict__ xlo,
    unsigned short* __restrict__ ehi, unsigned short* __restrict__ elo,
    float* __restrict__ e_norm, float* __restrict__ esumT,
    float* __restrict__ onehot, float* __restrict__ scal,
    unsigned long long* __restrict__ partials) {
  __shared__ float tile[32][33];
  __shared__ float part[8][32];
  __shared__ float w[4];
  const int bid = blockIdx.x;
  const int tid = threadIdx.x;

  if (bid < 8192) {
    const size_t i = ((size_t)bid * 256 + tid) * 8;
    const float4 v0 = *(const float4*)&x[i];
    const float4 v1 = *(const float4*)&x[i + 4];
    const float v[8] = {v0.x, v0.y, v0.z, v0.w, v1.x, v1.y, v1.z, v1.w};
    unsigned short h[8], l[8];
#pragma unroll
    for (int j = 0; j < 8; ++j) {
      h[j] = bf16rne(v[j]);
      l[j] = bf16rne(v[j] - __uint_as_float((unsigned)h[j] << 16));
    }
    uint4 H, L;
    H.x = h[0] | ((unsigned)h[1] << 16); H.y = h[2] | ((unsigned)h[3] << 16);
    H.z = h[4] | ((unsigned)h[5] << 16); H.w = h[6] | ((unsigned)h[7] << 16);
    L.x = l[0] | ((unsigned)l[1] << 16); L.y = l[2] | ((unsigned)l[3] << 16);
    L.z = l[4] | ((unsigned)l[5] << 16); L.w = l[6] | ((unsigned)l[7] << 16);
    *(uint4*)&xhi[i] = H;
    *(uint4*)&xlo[i] = L;
  } else if (bid < 8192 + 256) {
    const int k0 = (bid - 8192) * 32;
    const int tx = tid & 31;
    const int ty = tid >> 5;
    float sq = 0.f;
#pragma unroll 1
    for (int d0 = 0; d0 < DDIM; d0 += 32) {
      __syncthreads();
#pragma unroll
      for (int j = 0; j < 4; ++j) {
        const int dl = ty + j * 8;
        const float v = embed[(size_t)(d0 + dl) * KCODES + k0 + tx];
        tile[dl][tx] = v;
        sq += v * v;
      }
      __syncthreads();
#pragma unroll
      for (int j = 0; j < 4; ++j) {
        const int kl = ty + j * 8;
        const size_t idx = (size_t)(k0 + kl) * DDIM + d0 + tx;
        const float v = tile[tx][kl];
        const unsigned short h = bf16rne(v);
        ehi[idx] = h;
        elo[idx] = bf16rne(v - __uint_as_float((unsigned)h << 16));
      }
    }
    part[ty][tx] = sq;
    __syncthreads();
    if (ty == 0) {
      float s = 0.f;
#pragma unroll
      for (int j = 0; j < 8; ++j) s += part[j][tx];
      e_norm[k0 + tx] = s;
    }
  } else if (bid < 8192 + 256 + 2048) {
    const int zb = bid - (8192 + 256);
    const size_t off = (size_t)zb * 2048 + (size_t)tid * 8;
    const float4 z = {0.f, 0.f, 0.f, 0.f};
    *(float4*)&esumT[off] = z;
    *(float4*)&esumT[off + 4] = z;
  } else {
    const int b = bid - (8192 + 256 + 2048);    // 0..31
    onehot[b * 256 + tid] = 0.f;
    const size_t pbase = (size_t)b * 1024 + (size_t)tid * 4;
    const ulonglong2 ff = {~0ull, ~0ull};
    *(ulonglong2*)&partials[pbase] = ff;
    *(ulonglong2*)&partials[pbase + 2] = ff;
    float s = cluster_size[b * 256 + tid];
#pragma unroll
    for (int off = 32; off > 0; off >>= 1) s += __shfl_down(s, off);
    if ((tid & 63) == 0) w[tid >> 6] = s;
    __syncthreads();
    if (tid == 0) {
      scal[2 + b] = w[0] + w[1] + w[2] + w[3];
      if (b == 0) { scal[0] = 0.f; scal[1] = 0.f; }
    }
  }
}

// ============ K2: 256x256 8-phase-style dist GEMM (K'=1536) + argmin ============
// Standard-GEMM reformulation: A''=[xhi|xhi|xlo], B''=[ehi|elo|ehi] along K'.
// Template: BK=64, 8 waves (2x4), 128 KB LDS dbuf, per-phase half-tile staging,
// counted vmcnt gates (6 at tile boundary, 8 mid-tile), XOR swizzle both sides.
#define PHASE_MFMA(Q) do {                                                  \
  __builtin_amdgcn_s_setprio(1);                                            \
  _Pragma("unroll") for (int fm_ = 0; fm_ < 4; ++fm_)                       \
  _Pragma("unroll") for (int fn_ = 0; fn_ < 2; ++fn_)                       \
  _Pragma("unroll") for (int ks_ = 0; ks_ < 2; ++ks_)                       \
    acc[Q][fm_][fn_] = __builtin_amdgcn_mfma_f32_16x16x32_bf16(             \
        Areg[fm_][ks_], Breg[fn_][ks_], acc[Q][fm_][fn_], 0, 0, 0);         \
  __builtin_amdgcn_s_setprio(0);                                            \
} while (0)

__global__ __launch_bounds__(512, 2) void argmin_mfma_kernel(
    const unsigned short* __restrict__ xhi, const unsigned short* __restrict__ xlo,
    const unsigned short* __restrict__ ehi, const unsigned short* __restrict__ elo,
    const float* __restrict__ e_norm, unsigned long long* __restrict__ partials) {
  __shared__ unsigned short sA[2][2][128 * 64];   // [buf][half][row*64+col] 64 KB
  __shared__ unsigned short sB[2][2][128 * 64];   // 64 KB

  const int tid = threadIdx.x;
  const int wid = tid >> 6;          // 0..7
  const int lid = tid & 63;
  const int wr  = wid >> 2;          // 0..1  token 64-row band within quadrant
  const int wc  = wid & 3;           // 0..3  code 32-col band within quadrant
  const int m16 = lid & 15, kq = lid >> 4;
  const int kbase   = blockIdx.x * 256;
  const int tokbase = blockIdx.y * 256;

  // staging constants: wave-instr q covers rows w2q*8..+8, lane -> (row=l8, grp=g8)
  // LDS[row][g] = global[row][g ^ (row&7)]  (pre-swizzled source, linear dest)
  const int w2q0 = wid * 2, w2q1 = w2q0 + 1;
  const int l8 = lid >> 3, g8 = lid & 7;
  const size_t sgo0 = (size_t)(w2q0 * 8 + l8) * DDIM + (size_t)((g8 ^ l8) * 8);
  const size_t sgo1 = (size_t)(w2q1 * 8 + l8) * DDIM + (size_t)((g8 ^ l8) * 8);

  f32x4 acc[4][4][2];
#pragma unroll
  for (int q = 0; q < 4; ++q)
#pragma unroll
    for (int i = 0; i < 4; ++i)
#pragma unroll
      for (int j = 0; j < 2; ++j) acc[q][i][j] = (f32x4)0.f;

  short8 Areg[4][2];
  short8 Breg[2][2];

  auto stageA = [&](int h, int kt, int bf) {
    const int ktc = kt < 24 ? kt : 23;
    const unsigned short* sp = (ktc < 16 ? xhi : xlo)
        + (size_t)(tokbase + h * 128) * DDIM + ((ktc & 7) << 6);
    gload_lds16(sp + sgo0, &sA[bf][h][w2q0 * 512]);
    gload_lds16(sp + sgo1, &sA[bf][h][w2q1 * 512]);
  };
  auto stageB = [&](int h, int kt, int bf) {
    const int ktc = kt < 24 ? kt : 23;
    const unsigned short* sp = ((ktc >= 8 && ktc < 16) ? elo : ehi)
        + (size_t)(kbase + h * 128) * DDIM + ((ktc & 7) << 6);
    gload_lds16(sp + sgo0, &sB[bf][h][w2q0 * 512]);
    gload_lds16(sp + sgo1, &sB[bf][h][w2q1 * 512]);
  };
  auto loadA = [&](int bf, int mh) {
#pragma unroll
    for (int fm = 0; fm < 4; ++fm)
#pragma unroll
      for (int ks = 0; ks < 2; ++ks) {
        const int r = wr * 64 + fm * 16 + m16;
        const int grp = (ks * 4 + kq) ^ (m16 & 7);
        Areg[fm][ks] = *(const short8*)&sA[bf][mh][r * 64 + grp * 8];
      }
  };
  auto loadB = [&](int bf, int nh) {
#pragma unroll
    for (int fn = 0; fn < 2; ++fn)
#pragma unroll
      for (int ks = 0; ks < 2; ++ks) {
        const int r = wc * 32 + fn * 16 + m16;
        const int grp = (ks * 4 + kq) ^ (m16 & 7);
        Breg[fn][ks] = *(const short8*)&sB[bf][nh][r * 64 + grp * 8];
      }
  };

  // ---- prologue: tile0 all halves + tile1 {B0, A1}; gate leaves 3 in flight ----
  stageA(0, 0, 0); stageB(0, 0, 0); stageA(1, 0, 0); stageB(1, 0, 0);
  stageB(0, 1, 1); stageA(1, 1, 1);
  VMCNT6();
  BAR();

  // ---- K-loop: 24 tiles, 4 quadrant-phases each ----
  // quadrants: q0=(mh0,nh0) q1=(mh1,nh0) q2=(mh1,nh1) q3=(mh0,nh1)
  // staging:   p1: A0(s+1)->nxt  p2: B1(s+1)->nxt  p3: B0(s+2)->cur  p4: A1(s+2)->cur
#pragma unroll 1
  for (int s = 0; s < 24; ++s) {
    const int cur = s & 1, nxt = cur ^ 1;
    // phase 1
    loadA(cur, 0); loadB(cur, 0);
    stageA(0, s + 1, nxt);
    BAR();
    PHASE_MFMA(0);
    BAR();
    // phase 2
    loadA(cur, 1);
    stageB(1, s + 1, nxt);
    BAR();
    PHASE_MFMA(1);
    VMCNT8();
    BAR();
    // phase 3
    loadB(cur, 1);
    stageB(0, s + 2, cur);
    BAR();
    PHASE_MFMA(2);
    BAR();
    // phase 4
    loadA(cur, 0);
    stageA(1, s + 2, cur);
    BAR();
    PHASE_MFMA(3);
    VMCNT6();
    BAR();
  }

  // ---- epilogue: score = ||e_k||^2 - 2*dot, argmin over 256 codes ----
  asm volatile("s_waitcnt vmcnt(0)" ::: "memory");
  __syncthreads();

  float en[2][2];
#pragma unroll
  for (int nh = 0; nh < 2; ++nh)
#pragma unroll
    for (int fn = 0; fn < 2; ++fn)
      en[nh][fn] = e_norm[kbase + nh * 128 + wc * 32 + fn * 16 + m16];

  unsigned long long* red = (unsigned long long*)&sA[0][0][0];   // [256][8]
  const int mh_arr[4] = {0, 1, 1, 0};
  const int nh_arr[4] = {0, 0, 1, 1};
#pragma unroll
  for (int q = 0; q < 4; ++q) {
    const int mh = mh_arr[q], nh = nh_arr[q];
#pragma unroll
    for (int fm = 0; fm < 4; ++fm) {
#pragma unroll
      for (int r = 0; r < 4; ++r) {
        unsigned long long best = 0xFFFFFFFFFFFFFFFFull;
#pragma unroll
        for (int fn = 0; fn < 2; ++fn) {
          const float sc = en[nh][fn] - 2.0f * acc[q][fm][fn][r];
          unsigned u = __float_as_uint(sc);
          u = (u & 0x80000000u) ? ~u : (u | 0x80000000u);
          const unsigned k = (unsigned)(kbase + nh * 128 + wc * 32 + fn * 16 + m16);
          const unsigned long long c = ((unsigned long long)u << 32) | k;
          best = (c < best) ? c : best;
        }
#pragma unroll
        for (int sh = 1; sh < 16; sh <<= 1) {
          const unsigned long long c = __shfl_xor(best, sh);
          best = (c < best) ? c : best;
        }
        if (m16 == 0)
          red[(mh * 128 + wr * 64 + fm * 16 + kq * 4 + r) * 8 + nh * 4 + wc] = best;
      }
    }
  }
  __syncthreads();
  if (tid < 256) {
    unsigned long long m = red[tid * 8];
#pragma unroll
    for (int c = 1; c < 8; ++c) {
      const unsigned long long v = red[tid * 8 + c];
      m = (v < m) ? v : m;
    }
    atomicMin(&partials[tokbase + tid], m);
  }
}

// ============ K3: gather quantize + EMA scatter stats + loss (unchanged) ============
__global__ __launch_bounds__(256) void gather_stats_kernel(
    const float* __restrict__ x, const unsigned short* __restrict__ ehi,
    const unsigned short* __restrict__ elo,
    const unsigned long long* __restrict__ partials,
    float* __restrict__ quant_out, float* __restrict__ indf_out,
    float* __restrict__ embed_sumT, float* __restrict__ onehot,
    float* __restrict__ scal) {
  const int sub = threadIdx.x >> 7;          // 0/1: which token
  const int t7  = threadIdx.x & 127;
  const int n   = blockIdx.x * 2 + sub;
  __shared__ int s_ind[2];
  __shared__ float wsum[4];
  if (t7 == 0) {
    const int k = (int)(partials[n] & 0xFFFFFFFFull);
    s_ind[sub] = k;
    indf_out[n] = (float)k;
    atomicAdd(&onehot[k], 1.0f);
  }
  __syncthreads();
  const int k = s_ind[sub];
  const int d4 = t7 * 4;
  const ushort4 h4 = *(const ushort4*)&ehi[(size_t)k * DDIM + d4];
  const ushort4 l4 = *(const ushort4*)&elo[(size_t)k * DDIM + d4];
  float4 e;
  e.x = __uint_as_float((unsigned)h4.x << 16) + __uint_as_float((unsigned)l4.x << 16);
  e.y = __uint_as_float((unsigned)h4.y << 16) + __uint_as_float((unsigned)l4.y << 16);
  e.z = __uint_as_float((unsigned)h4.z << 16) + __uint_as_float((unsigned)l4.z << 16);
  e.w = __uint_as_float((unsigned)h4.w << 16) + __uint_as_float((unsigned)l4.w << 16);
  const float4 xv = *(const float4*)&x[(size_t)n * DDIM + d4];
  *(float4*)&quant_out[(size_t)n * DDIM + d4] = e;
  atomicAdd(&embed_sumT[(size_t)k * DDIM + d4 + 0], xv.x);
  atomicAdd(&embed_sumT[(size_t)k * DDIM + d4 + 1], xv.y);
  atomicAdd(&embed_sumT[(size_t)k * DDIM + d4 + 2], xv.z);
  atomicAdd(&embed_sumT[(size_t)k * DDIM + d4 + 3], xv.w);
  const float dx0 = e.x - xv.x, dx1 = e.y - xv.y, dx2 = e.z - xv.z, dx3 = e.w - xv.w;
  float ls = dx0 * dx0 + dx1 * dx1 + dx2 * dx2 + dx3 * dx3;
#pragma unroll
  for (int off = 32; off > 0; off >>= 1) ls += __shfl_down(ls, off);
  if ((threadIdx.x & 63) == 0) wsum[threadIdx.x >> 6] = ls;
  __syncthreads();
  if (threadIdx.x == 0)
    atomicAdd(&scal[0], wsum[0] + wsum[1] + wsum[2] + wsum[3]);
}

// ============ K4: finalize (unchanged) ============
__global__ __launch_bounds__(256) void finalize_kernel(
    const float* __restrict__ embed_avg, const float* __restrict__ embed_sumT,
    const float* __restrict__ cluster_size, const float* __restrict__ onehot,
    const float* __restrict__ scal,
    float* __restrict__ out_embed, float* __restrict__ out_avg,
    float* __restrict__ out_ncs, float* __restrict__ out_loss) {
  __shared__ float tile[32][33];
  __shared__ float sh_nsum;
  const int k0 = blockIdx.x * 32;
  const int d0 = blockIdx.y * 32;
  const int tx = threadIdx.x & 31;
  const int ty = threadIdx.x >> 5;
  if (threadIdx.x == 0) {
    float s = 0.f;
#pragma unroll
    for (int b = 0; b < 32; ++b) s += scal[2 + b];
    sh_nsum = DECAYF * s + (1.0f - DECAYF) * (float)NTOK;
  }
#pragma unroll
  for (int j = 0; j < 4; ++j) {
    const int kl = ty + j * 8;
    tile[kl][tx] = embed_sumT[(size_t)(k0 + kl) * DDIM + d0 + tx];
  }
  __syncthreads();
  const float nsum = sh_nsum;
  const float ncs = DECAYF * cluster_size[k0 + tx] + (1.0f - DECAYF) * onehot[k0 + tx];
  const float csv = (ncs + EPSF) / (nsum + (float)KCODES * EPSF) * nsum;
#pragma unroll
  for (int j = 0; j < 4; ++j) {
    const int dl = ty + j * 8;
    const size_t idx = (size_t)(d0 + dl) * KCODES + k0 + tx;
    const float nea = DECAYF * embed_avg[idx] + (1.0f - DECAYF) * tile[tx][dl];
    out_avg[idx] = nea;
    out_embed[idx] = nea / csv;
  }
  if (blockIdx.y == 0 && ty == 0)
    out_ncs[k0 + tx] = ncs;
  if (blockIdx.x == 0 && blockIdx.y == 0 && threadIdx.x == 0)
    out_loss[0] = scal[0] * (1.0f / ((float)NTOK * (float)DDIM));
}

extern "C" void kernel_launch(void* const* d_in, const int* in_sizes, int n_in,
                              void* d_out, int out_size, void* d_ws, size_t ws_size,
                              hipStream_t stream) {
  (void)in_sizes; (void)n_in; (void)out_size; (void)ws_size;
  const float* x            = (const float*)d_in[0];   // [NTOK, 512]
  const float* embed        = (const float*)d_in[1];   // [D, K]
  const float* cluster_size = (const float*)d_in[2];   // [K]
  const float* embed_avg    = (const float*)d_in[3];   // [D, K]

  float* out = (float*)d_out;
  float* out_quant = out;                               // 16777216
  float* out_indf  = out + 16777216;                    // 32768
  float* out_loss  = out + 16777216 + 32768;            // 1
  float* out_embed = out + 16777216 + 32768 + 1;        // 4194304 (odd offset)
  float* out_ncs   = out_embed + DK;                    // 8192
  float* out_avg   = out_ncs + KCODES;                  // 4194304

  float* ws = (float*)d_ws;
  float* esumT  = ws + WS_ESUMT;
  float* onehot = ws + WS_ONEHOT;
  float* e_norm = ws + WS_ENORM;
  float* scal   = ws + WS_SCAL;
  unsigned long long* partials = (unsigned long long*)(ws + WS_PART);
  unsigned short* ehi = (unsigned short*)(ws + WS_EHI);
  unsigned short* elo = (unsigned short*)(ws + WS_ELO);

  // x hi/lo scratch lives in the out_quant region; overwritten by gather later.
  unsigned short* xhi = (unsigned short*)d_out;
  unsigned short* xlo = xhi + (size_t)NTOK * DDIM;

  prep_kernel<<<8192 + 256 + 2048 + 32, 256, 0, stream>>>(
      x, embed, cluster_size, xhi, xlo, ehi, elo, e_norm, esumT, onehot, scal, partials);

  argmin_mfma_kernel<<<dim3(KCODES / 256, NTOK / 256), 512, 0, stream>>>(
      xhi, xlo, ehi, elo, e_norm, partials);

  gather_stats_kernel<<<NTOK / 2, 256, 0, stream>>>(
      x, ehi, elo, partials, out_quant, out_indf, esumT, onehot, scal);

  finalize_kernel<<<dim3(KCODES / 32, DDIM / 32), 256, 0, stream>>>(
      embed_avg, esumT, cluster_size, onehot, scal,
      out_embed, out_avg, out_ncs, out_loss);
}